// Round 2
// baseline (157.598 us; speedup 1.0000x reference)
//
#include <hip/hip_runtime.h>
#include <math.h>

// ---------------------------------------------------------------------------
// Scattering (J=2,L=8,N=32) + GroupNorm(27) fused into ONE kernel (192 blocks,
// one per (b,color); groups never straddle colors since 81 = 9*9 channels),
// then a GEMV kernel. u0f never leaves LDS.
// ---------------------------------------------------------------------------

constexpr float C32T[32] = {
  1.0000000000f, 0.9807852804f, 0.9238795325f, 0.8314696123f,
  0.7071067812f, 0.5555702330f, 0.3826834324f, 0.1950903220f,
  0.0000000000f,-0.1950903220f,-0.3826834324f,-0.5555702330f,
 -0.7071067812f,-0.8314696123f,-0.9238795325f,-0.9807852804f,
 -1.0000000000f,-0.9807852804f,-0.9238795325f,-0.8314696123f,
 -0.7071067812f,-0.5555702330f,-0.3826834324f,-0.1950903220f,
  0.0000000000f, 0.1950903220f, 0.3826834324f, 0.5555702330f,
  0.7071067812f, 0.8314696123f, 0.9238795325f, 0.9807852804f };
constexpr float S32T[32] = {
  0.0000000000f, 0.1950903220f, 0.3826834324f, 0.5555702330f,
  0.7071067812f, 0.8314696123f, 0.9238795325f, 0.9807852804f,
  1.0000000000f, 0.9807852804f, 0.9238795325f, 0.8314696123f,
  0.7071067812f, 0.5555702330f, 0.3826834324f, 0.1950903220f,
  0.0000000000f,-0.1950903220f,-0.3826834324f,-0.5555702330f,
 -0.7071067812f,-0.8314696123f,-0.9238795325f,-0.9807852804f,
 -1.0000000000f,-0.9807852804f,-0.9238795325f,-0.8314696123f,
 -0.7071067812f,-0.5555702330f,-0.3826834324f,-0.1950903220f };

template<int N, bool INV>
__device__ __forceinline__ void fft1d(float2 (&a)[N]) {
  constexpr int LOG = (N == 32) ? 5 : ((N == 16) ? 4 : 3);
  #pragma unroll
  for (int i = 0; i < N; ++i) {
    int j = 0;
    #pragma unroll
    for (int bn = 0; bn < LOG; ++bn) j |= ((i >> bn) & 1) << (LOG - 1 - bn);
    if (j > i) { float2 t = a[i]; a[i] = a[j]; a[j] = t; }
  }
  #pragma unroll
  for (int s = 1; s <= LOG; ++s) {
    const int half  = 1 << (s - 1);
    const int tstep = 32 >> s;
    #pragma unroll
    for (int i = 0; i < N; i += (1 << s)) {
      #pragma unroll
      for (int k = 0; k < half; ++k) {
        const int   ti = k * tstep;
        const float wr = C32T[ti];
        const float wi = INV ? S32T[ti] : -S32T[ti];
        const float2 u = a[i + k];
        const float2 v = a[i + k + half];
        const float tr = v.x * wr - v.y * wi;
        const float tq = v.x * wi + v.y * wr;
        a[i + k]        = make_float2(u.x + tr, u.y + tq);
        a[i + k + half] = make_float2(u.x - tr, u.y - tq);
      }
    }
  }
}

template<int N, bool INV>
__device__ __forceinline__ void fft_row(float* re, float* im, int row, int LD) {
  float2 a[N];
  #pragma unroll
  for (int i = 0; i < N; ++i) a[i] = make_float2(re[row * LD + i], im[row * LD + i]);
  fft1d<N, INV>(a);
  #pragma unroll
  for (int i = 0; i < N; ++i) { re[row * LD + i] = a[i].x; im[row * LD + i] = a[i].y; }
}

template<int N, bool INV>
__device__ __forceinline__ void fft_col(float* re, float* im, int col, int LD) {
  float2 a[N];
  #pragma unroll
  for (int i = 0; i < N; ++i) a[i] = make_float2(re[i * LD + col], im[i * LD + col]);
  fft1d<N, INV>(a);
  #pragma unroll
  for (int i = 0; i < N; ++i) { re[i * LD + col] = a[i].x; im[i * LD + col] = a[i].y; }
}

// ---------------------------------------------------------------------------
// Kernel A: full scattering for one (b,c) + GroupNorm of its 9 groups.
// grid = 192, block = 256.  LDS ~139 KB (1 block/CU; only 192 blocks total).
// ---------------------------------------------------------------------------
__global__ __launch_bounds__(256) void k_scatter_gn(
    const float* __restrict__ x, const float* __restrict__ psi0,
    const float* __restrict__ psi1, const float* __restrict__ phi,
    const float* __restrict__ gamma, const float* __restrict__ beta,
    float* __restrict__ featn)
{
  __shared__ float Xr[1056], Xi[1056];   // 32x33 xf
  __shared__ float Ar[8448], Ai[8448];   // 8 x 32x33: u0 -> u0f (stays in LDS)
  __shared__ float Cr[4352], Ci[4352];   // 16 x 16x17: u1 planes / order-2 planes
  __shared__ float Sr[1152], Si[1152];   // 16 x 8x9
  __shared__ float P1[272];              // 16x17 phi at res 1
  __shared__ float F[5184];              // 81 channels x 64 (this block's features)
  __shared__ float gmu[9], grs[9];
  const int tid = threadIdx.x;
  const int bc  = blockIdx.x;
  const int b = bc / 3, c = bc % 3;
  const float* xp = x + bc * 1024;

  for (int e = tid; e < 1024; e += 256) {
    const int r = e >> 5, cc = e & 31;
    Xr[r * 33 + cc] = xp[e];
    Xi[r * 33 + cc] = 0.0f;
  }
  { const int u = tid >> 4, v = tid & 15;
    P1[u * 17 + v] = 0.25f * (phi[u * 32 + v] + phi[u * 32 + v + 16] +
                              phi[(u + 16) * 32 + v] + phi[(u + 16) * 32 + v + 16]); }
  __syncthreads();

  // xf = fft2(x)
  if (tid < 32) fft_row<32, false>(Xr, Xi, tid, 33);
  __syncthreads();
  if (tid < 32) fft_col<32, false>(Xr, Xi, tid, 33);
  __syncthreads();

  // ---- order 1, j1=0: A[p] = xf * psi0[p]; u0 = |ifft2|; u0f = fft2(u0) ----
  for (int e = tid; e < 8192; e += 256) {
    const int p = e >> 10, rc = e & 1023, r = rc >> 5, cc = rc & 31;
    const float ps = psi0[e];
    Ar[p * 1056 + r * 33 + cc] = Xr[r * 33 + cc] * ps;
    Ai[p * 1056 + r * 33 + cc] = Xi[r * 33 + cc] * ps;
  }
  __syncthreads();
  { const int p = tid >> 5, r = tid & 31; fft_row<32, true>(Ar + p * 1056, Ai + p * 1056, r, 33); }
  __syncthreads();
  { const int p = tid >> 5, col = tid & 31;
    float* re = Ar + p * 1056; float* im = Ai + p * 1056;
    float2 a[32];
    #pragma unroll
    for (int i = 0; i < 32; ++i) a[i] = make_float2(re[i * 33 + col], im[i * 33 + col]);
    fft1d<32, true>(a);
    #pragma unroll
    for (int i = 0; i < 32; ++i) {
      const float m = sqrtf(a[i].x * a[i].x + a[i].y * a[i].y) * (1.0f / 1024.0f);
      a[i] = make_float2(m, 0.0f);
    }
    fft1d<32, false>(a);
    #pragma unroll
    for (int i = 0; i < 32; ++i) { re[i * 33 + col] = a[i].x; im[i * 33 + col] = a[i].y; }
  }
  __syncthreads();
  { const int p = tid >> 5, r = tid & 31; fft_row<32, false>(Ar + p * 1056, Ai + p * 1056, r, 33); }
  __syncthreads();

  // ---- s0 (p==8 from xf) and s1a (p=0..7 from u0f): 4x4 alias sum * phi ----
  for (int e = tid; e < 576; e += 256) {
    const int p = e >> 6, u = (e >> 3) & 7, v = e & 7;
    float sr = 0.f, si = 0.f;
    #pragma unroll
    for (int i2 = 0; i2 < 4; ++i2)
      #pragma unroll
      for (int j2 = 0; j2 < 4; ++j2) {
        const int r = u + 8 * i2, cc = v + 8 * j2;
        const float ph = phi[r * 32 + cc];
        float vr, vi;
        if (p == 8) { vr = Xr[r * 33 + cc]; vi = Xi[r * 33 + cc]; }
        else        { vr = Ar[p * 1056 + r * 33 + cc]; vi = Ai[p * 1056 + r * 33 + cc]; }
        sr += vr * ph; si += vi * ph;
      }
    Sr[p * 72 + u * 9 + v] = sr * 0.0625f;
    Si[p * 72 + u * 9 + v] = si * 0.0625f;
  }
  __syncthreads();
  if (tid < 72) { const int p = tid >> 3, r = tid & 7; fft_row<8, true>(Sr + p * 72, Si + p * 72, r, 9); }
  __syncthreads();
  if (tid < 72) {
    const int p = tid >> 3, col = tid & 7;
    float2 a[8];
    #pragma unroll
    for (int i = 0; i < 8; ++i) a[i] = make_float2(Sr[p * 72 + i * 9 + col], Si[p * 72 + i * 9 + col]);
    fft1d<8, true>(a);
    const int ch = (p == 8) ? 0 : (1 + p);
    #pragma unroll
    for (int i = 0; i < 8; ++i) F[ch * 64 + i * 8 + col] = a[i].x * (1.0f / 64.0f);
  }
  // (no barrier needed: next phase writes Cr, untouched by the fft8 stage;
  //  Xr/Xi are stable)

  // ---- order 1, j1=1: C[p] = sub(xf*psi1[p],2), 16x16 modulus path ----
  for (int e = tid; e < 2048; e += 256) {
    const int p = e >> 8, u = (e >> 4) & 15, v = e & 15;
    float sr = 0.f, si = 0.f;
    #pragma unroll
    for (int i2 = 0; i2 < 2; ++i2)
      #pragma unroll
      for (int j2 = 0; j2 < 2; ++j2) {
        const int r = u + 16 * i2, cc = v + 16 * j2;
        const float ps = psi1[p * 1024 + r * 32 + cc];
        sr += Xr[r * 33 + cc] * ps; si += Xi[r * 33 + cc] * ps;
      }
    Cr[p * 272 + u * 17 + v] = 0.25f * sr;
    Ci[p * 272 + u * 17 + v] = 0.25f * si;
  }
  __syncthreads();
  if (tid < 128) { const int p = tid >> 4, r = tid & 15; fft_row<16, true>(Cr + p * 272, Ci + p * 272, r, 17); }
  __syncthreads();
  if (tid < 128) {
    const int p = tid >> 4, col = tid & 15;
    float* re = Cr + p * 272; float* im = Ci + p * 272;
    float2 a[16];
    #pragma unroll
    for (int i = 0; i < 16; ++i) a[i] = make_float2(re[i * 17 + col], im[i * 17 + col]);
    fft1d<16, true>(a);
    #pragma unroll
    for (int i = 0; i < 16; ++i) {
      const float m = sqrtf(a[i].x * a[i].x + a[i].y * a[i].y) * (1.0f / 256.0f);
      a[i] = make_float2(m, 0.0f);
    }
    fft1d<16, false>(a);
    #pragma unroll
    for (int i = 0; i < 16; ++i) { re[i * 17 + col] = a[i].x; im[i * 17 + col] = a[i].y; }
  }
  __syncthreads();
  if (tid < 128) { const int p = tid >> 4, r = tid & 15; fft_row<16, false>(Cr + p * 272, Ci + p * 272, r, 17); }
  __syncthreads();
  for (int e = tid; e < 512; e += 256) {
    const int p = e >> 6, u = (e >> 3) & 7, v = e & 7;
    float sr = 0.f, si = 0.f;
    #pragma unroll
    for (int i2 = 0; i2 < 2; ++i2)
      #pragma unroll
      for (int j2 = 0; j2 < 2; ++j2) {
        const int r = u + 8 * i2, cc = v + 8 * j2;
        const float ph = P1[r * 17 + cc];
        sr += Cr[p * 272 + r * 17 + cc] * ph;
        si += Ci[p * 272 + r * 17 + cc] * ph;
      }
    Sr[p * 72 + u * 9 + v] = 0.25f * sr;
    Si[p * 72 + u * 9 + v] = 0.25f * si;
  }
  __syncthreads();
  if (tid < 64) { const int p = tid >> 3, r = tid & 7; fft_row<8, true>(Sr + p * 72, Si + p * 72, r, 9); }
  __syncthreads();
  if (tid < 64) {
    const int p = tid >> 3, col = tid & 7;
    float2 a[8];
    #pragma unroll
    for (int i = 0; i < 8; ++i) a[i] = make_float2(Sr[p * 72 + i * 9 + col], Si[p * 72 + i * 9 + col]);
    fft1d<8, true>(a);
    #pragma unroll
    for (int i = 0; i < 8; ++i) F[(9 + p) * 64 + i * 8 + col] = a[i].x * (1.0f / 64.0f);
  }
  __syncthreads();   // Cr/Sr about to be reused

  // ---- order 2: 64 (t1,t2) planes in 4 rounds of 16; source u0f in Ar ----
  for (int round = 0; round < 4; ++round) {
    for (int e = tid; e < 4096; e += 256) {
      const int q = e >> 8, u = (e >> 4) & 15, v = e & 15;
      const int pp = round * 16 + q, t1 = pp >> 3, t2 = pp & 7;
      float sr = 0.f, si = 0.f;
      #pragma unroll
      for (int i2 = 0; i2 < 2; ++i2)
        #pragma unroll
        for (int j2 = 0; j2 < 2; ++j2) {
          const int r = u + 16 * i2, cc = v + 16 * j2;
          const float ps = psi1[t2 * 1024 + r * 32 + cc];
          sr += Ar[t1 * 1056 + r * 33 + cc] * ps;
          si += Ai[t1 * 1056 + r * 33 + cc] * ps;
        }
      Cr[q * 272 + u * 17 + v] = 0.25f * sr;
      Ci[q * 272 + u * 17 + v] = 0.25f * si;
    }
    __syncthreads();
    { const int q = tid >> 4, r = tid & 15; fft_row<16, true>(Cr + q * 272, Ci + q * 272, r, 17); }
    __syncthreads();
    { const int q = tid >> 4, col = tid & 15;
      float* re = Cr + q * 272; float* im = Ci + q * 272;
      float2 a[16];
      #pragma unroll
      for (int i = 0; i < 16; ++i) a[i] = make_float2(re[i * 17 + col], im[i * 17 + col]);
      fft1d<16, true>(a);
      #pragma unroll
      for (int i = 0; i < 16; ++i) {
        const float m = sqrtf(a[i].x * a[i].x + a[i].y * a[i].y) * (1.0f / 256.0f);
        a[i] = make_float2(m, 0.0f);
      }
      fft1d<16, false>(a);
      #pragma unroll
      for (int i = 0; i < 16; ++i) { re[i * 17 + col] = a[i].x; im[i * 17 + col] = a[i].y; }
    }
    __syncthreads();
    { const int q = tid >> 4, r = tid & 15; fft_row<16, false>(Cr + q * 272, Ci + q * 272, r, 17); }
    __syncthreads();
    for (int e = tid; e < 1024; e += 256) {
      const int q = e >> 6, u = (e >> 3) & 7, v = e & 7;
      float sr = 0.f, si = 0.f;
      #pragma unroll
      for (int i2 = 0; i2 < 2; ++i2)
        #pragma unroll
        for (int j2 = 0; j2 < 2; ++j2) {
          const int r = u + 8 * i2, cc = v + 8 * j2;
          const float ph = P1[r * 17 + cc];
          sr += Cr[q * 272 + r * 17 + cc] * ph;
          si += Ci[q * 272 + r * 17 + cc] * ph;
        }
      Sr[q * 72 + u * 9 + v] = 0.25f * sr;
      Si[q * 72 + u * 9 + v] = 0.25f * si;
    }
    __syncthreads();
    if (tid < 128) { const int q = tid >> 3, r = tid & 7; fft_row<8, true>(Sr + q * 72, Si + q * 72, r, 9); }
    __syncthreads();
    if (tid < 128) {
      const int q = tid >> 3, col = tid & 7;
      float2 a[8];
      #pragma unroll
      for (int i = 0; i < 8; ++i) a[i] = make_float2(Sr[q * 72 + i * 9 + col], Si[q * 72 + i * 9 + col]);
      fft1d<8, true>(a);
      const int pp = round * 16 + q;
      #pragma unroll
      for (int i = 0; i < 8; ++i) F[(17 + pp) * 64 + i * 8 + col] = a[i].x * (1.0f / 64.0f);
    }
    __syncthreads();
  }

  // ---- GroupNorm: 9 groups x (9 ch x 64) = 576 values each, all in F ----
  if (tid < 144) {
    const int g = tid >> 4, l = tid & 15;
    float s = 0.f, ss = 0.f;
    for (int e = l; e < 576; e += 16) { const float v = F[g * 576 + e]; s += v; ss += v * v; }
    #pragma unroll
    for (int off = 1; off < 16; off <<= 1) {
      s  += __shfl_xor(s,  off, 16);
      ss += __shfl_xor(ss, off, 16);
    }
    if (l == 0) {
      const float mu = s * (1.0f / 576.0f);
      gmu[g] = mu;
      grs[g] = rsqrtf(ss * (1.0f / 576.0f) - mu * mu + 1e-5f);
    }
  }
  __syncthreads();
  float* outp = featn + (size_t)b * 15552 + c * 5184;
  for (int e = tid; e < 5184; e += 256) {
    const int idx = e >> 6;          // local channel 0..80
    const int g = idx / 9;           // local group 0..8
    const int ch = c * 81 + idx;     // global channel
    outp[e] = (F[e] - gmu[g]) * grs[g] * gamma[ch] + beta[ch];
  }
}

// ---------------------------------------------------------------------------
// Kernel B: Linear(15552 -> 10) + bias.  grid = B = 64, block = 256.
// ---------------------------------------------------------------------------
__global__ __launch_bounds__(256) void k_linear(
    const float* __restrict__ featn, const float* __restrict__ W,
    const float* __restrict__ bias, float* __restrict__ out)
{
  __shared__ float red[40];
  const int tid = threadIdx.x, b = blockIdx.x;
  const float* fp = featn + (size_t)b * 15552;
  float acc[10];
  #pragma unroll
  for (int k = 0; k < 10; ++k) acc[k] = 0.f;
  for (int e = tid; e < 15552; e += 256) {
    const float v = fp[e];
    #pragma unroll
    for (int k = 0; k < 10; ++k) acc[k] = fmaf(v, W[k * 15552 + e], acc[k]);
  }
  #pragma unroll
  for (int k = 0; k < 10; ++k) {
    float v = acc[k];
    #pragma unroll
    for (int off = 32; off > 0; off >>= 1) v += __shfl_down(v, off);
    if ((tid & 63) == 0) red[(tid >> 6) * 10 + k] = v;
  }
  __syncthreads();
  if (tid < 10) out[b * 10 + tid] = red[tid] + red[10 + tid] + red[20 + tid] + red[30 + tid] + bias[tid];
}

// ---------------------------------------------------------------------------
extern "C" void kernel_launch(void* const* d_in, const int* in_sizes, int n_in,
                              void* d_out, int out_size, void* d_ws, size_t ws_size,
                              hipStream_t stream) {
  (void)in_sizes; (void)n_in; (void)out_size; (void)ws_size;
  const float* x     = (const float*)d_in[0];
  const float* psi0  = (const float*)d_in[1];
  const float* psi1  = (const float*)d_in[2];
  const float* phi   = (const float*)d_in[3];
  const float* gamma = (const float*)d_in[4];
  const float* beta  = (const float*)d_in[5];
  const float* W     = (const float*)d_in[6];
  const float* bias  = (const float*)d_in[7];
  float* out = (float*)d_out;

  float* featn = (float*)d_ws;   // 64*15552 floats ~ 4 MB (normalized features)

  hipLaunchKernelGGL(k_scatter_gn, dim3(192), dim3(256), 0, stream,
                     x, psi0, psi1, phi, gamma, beta, featn);
  hipLaunchKernelGGL(k_linear, dim3(64), dim3(256), 0, stream, featn, W, bias, out);
}

// Round 3
// 153.041 us; speedup vs baseline: 1.0298x; 1.0298x over previous
//
#include <hip/hip_runtime.h>
#include <math.h>

// ---------------------------------------------------------------------------
// Scattering (J=2,L=8,N=32) + GroupNorm(27) + Linear(15552->10), round 3.
// 4 kernels, single-wave (64-thread) blocks for the scatter stages:
//   k_xf   (96 blocks) : fft2(x) -> xf (ws), s0 -> feat
//   k_u0   (768 blocks): per (bc, plane-pair): u0 path -> u0f (ws), s1a -> feat
//   k_o2  (3456 blocks): unified 16x16 modulus path: j1 (src xf) + order-2
//                        (src u0f), 4 planes/block -> s1b/s2 -> feat
//   k_gnlin (64 blocks) : GroupNorm + GEMV(float4) -> out
// ---------------------------------------------------------------------------

constexpr float C32T[32] = {
  1.0000000000f, 0.9807852804f, 0.9238795325f, 0.8314696123f,
  0.7071067812f, 0.5555702330f, 0.3826834324f, 0.1950903220f,
  0.0000000000f,-0.1950903220f,-0.3826834324f,-0.5555702330f,
 -0.7071067812f,-0.8314696123f,-0.9238795325f,-0.9807852804f,
 -1.0000000000f,-0.9807852804f,-0.9238795325f,-0.8314696123f,
 -0.7071067812f,-0.5555702330f,-0.3826834324f,-0.1950903220f,
  0.0000000000f, 0.1950903220f, 0.3826834324f, 0.5555702330f,
  0.7071067812f, 0.8314696123f, 0.9238795325f, 0.9807852804f };
constexpr float S32T[32] = {
  0.0000000000f, 0.1950903220f, 0.3826834324f, 0.5555702330f,
  0.7071067812f, 0.8314696123f, 0.9238795325f, 0.9807852804f,
  1.0000000000f, 0.9807852804f, 0.9238795325f, 0.8314696123f,
  0.7071067812f, 0.5555702330f, 0.3826834324f, 0.1950903220f,
  0.0000000000f,-0.1950903220f,-0.3826834324f,-0.5555702330f,
 -0.7071067812f,-0.8314696123f,-0.9238795325f,-0.9807852804f,
 -1.0000000000f,-0.9807852804f,-0.9238795325f,-0.8314696123f,
 -0.7071067812f,-0.5555702330f,-0.3826834324f,-0.1950903220f };

template<int N, bool INV>
__device__ __forceinline__ void fft1d(float2 (&a)[N]) {
  constexpr int LOG = (N == 32) ? 5 : ((N == 16) ? 4 : 3);
  #pragma unroll
  for (int i = 0; i < N; ++i) {
    int j = 0;
    #pragma unroll
    for (int bn = 0; bn < LOG; ++bn) j |= ((i >> bn) & 1) << (LOG - 1 - bn);
    if (j > i) { float2 t = a[i]; a[i] = a[j]; a[j] = t; }
  }
  #pragma unroll
  for (int s = 1; s <= LOG; ++s) {
    const int half  = 1 << (s - 1);
    const int tstep = 32 >> s;
    #pragma unroll
    for (int i = 0; i < N; i += (1 << s)) {
      #pragma unroll
      for (int k = 0; k < half; ++k) {
        const int   ti = k * tstep;
        const float wr = C32T[ti];
        const float wi = INV ? S32T[ti] : -S32T[ti];
        const float2 u = a[i + k];
        const float2 v = a[i + k + half];
        const float tr = v.x * wr - v.y * wi;
        const float tq = v.x * wi + v.y * wr;
        a[i + k]        = make_float2(u.x + tr, u.y + tq);
        a[i + k + half] = make_float2(u.x - tr, u.y - tq);
      }
    }
  }
}

template<int N, bool INV>
__device__ __forceinline__ void fft_row(float* re, float* im, int row, int LD) {
  float2 a[N];
  #pragma unroll
  for (int i = 0; i < N; ++i) a[i] = make_float2(re[row * LD + i], im[row * LD + i]);
  fft1d<N, INV>(a);
  #pragma unroll
  for (int i = 0; i < N; ++i) { re[row * LD + i] = a[i].x; im[row * LD + i] = a[i].y; }
}

template<int N, bool INV>
__device__ __forceinline__ void fft_col(float* re, float* im, int col, int LD) {
  float2 a[N];
  #pragma unroll
  for (int i = 0; i < N; ++i) a[i] = make_float2(re[i * LD + col], im[i * LD + col]);
  fft1d<N, INV>(a);
  #pragma unroll
  for (int i = 0; i < N; ++i) { re[i * LD + col] = a[i].x; im[i * LD + col] = a[i].y; }
}

// ---------------------------------------------------------------------------
// k_xf: 2 (b,c) per block. xf = fft2(x) -> ws; s0 -> feat ch0.
// grid 96, block 64.
// ---------------------------------------------------------------------------
__global__ __launch_bounds__(64) void k_xf(
    const float* __restrict__ x, const float* __restrict__ phi,
    float2* __restrict__ xf_g, float* __restrict__ feat)
{
  __shared__ float Xr[2112], Xi[2112];   // 2 x 32x33
  __shared__ float Sr[144],  Si[144];    // 2 x 8x9
  const int tid = threadIdx.x;
  const int bc0 = blockIdx.x * 2;

  for (int e = tid; e < 2048; e += 64) {
    const int s = e >> 10, rc = e & 1023, r = rc >> 5, c = rc & 31;
    Xr[s * 1056 + r * 33 + c] = x[(bc0 + s) * 1024 + rc];
    Xi[s * 1056 + r * 33 + c] = 0.0f;
  }
  __syncthreads();
  { const int s = tid >> 5, r = tid & 31; fft_row<32, false>(Xr + s * 1056, Xi + s * 1056, r, 33); }
  __syncthreads();
  { const int s = tid >> 5, col = tid & 31; fft_col<32, false>(Xr + s * 1056, Xi + s * 1056, col, 33); }
  __syncthreads();
  // store xf
  for (int e = tid; e < 2048; e += 64) {
    const int s = e >> 10, rc = e & 1023, r = rc >> 5, c = rc & 31;
    xf_g[(size_t)(bc0 + s) * 1024 + rc] =
        make_float2(Xr[s * 1056 + r * 33 + c], Xi[s * 1056 + r * 33 + c]);
  }
  // s0 subsample: (1/16) sum_{4x4} xf*phi
  for (int e = tid; e < 128; e += 64) {
    const int s = e >> 6, u = (e >> 3) & 7, v = e & 7;
    float sr = 0.f, si = 0.f;
    #pragma unroll
    for (int i2 = 0; i2 < 4; ++i2)
      #pragma unroll
      for (int j2 = 0; j2 < 4; ++j2) {
        const int r = u + 8 * i2, c = v + 8 * j2;
        const float ph = phi[r * 32 + c];
        sr += Xr[s * 1056 + r * 33 + c] * ph;
        si += Xi[s * 1056 + r * 33 + c] * ph;
      }
    Sr[s * 72 + u * 9 + v] = sr * 0.0625f;
    Si[s * 72 + u * 9 + v] = si * 0.0625f;
  }
  __syncthreads();
  if (tid < 16) { const int s = tid >> 3, r = tid & 7; fft_row<8, true>(Sr + s * 72, Si + s * 72, r, 9); }
  __syncthreads();
  if (tid < 16) {
    const int s = tid >> 3, col = tid & 7;
    float2 a[8];
    #pragma unroll
    for (int i = 0; i < 8; ++i) a[i] = make_float2(Sr[s * 72 + i * 9 + col], Si[s * 72 + i * 9 + col]);
    fft1d<8, true>(a);
    float* fo = feat + ((size_t)(bc0 + s) * 81 + 0) * 64;
    #pragma unroll
    for (int i = 0; i < 8; ++i) fo[i * 8 + col] = a[i].x * (1.0f / 64.0f);
  }
}

// ---------------------------------------------------------------------------
// k_u0: one block per (bc, pair): planes p0=pair*2, p0+1 of the j1=0 path.
// grid 768 (= 192*4), block 64.
// ---------------------------------------------------------------------------
__global__ __launch_bounds__(64) void k_u0(
    const float2* __restrict__ xf_g, const float* __restrict__ psi0,
    const float* __restrict__ phi, float2* __restrict__ u0f_g,
    float* __restrict__ feat)
{
  __shared__ float Ar[2112], Ai[2112];   // 2 x 32x33
  __shared__ float Sr[144],  Si[144];    // 2 x 8x9
  const int tid = threadIdx.x;
  const int blk = blockIdx.x;
  const int bc = blk >> 2, p0 = (blk & 3) * 2;
  const float2* xf = xf_g + (size_t)bc * 1024;

  // A[q] = xf * psi0[p0+q]
  for (int e = tid; e < 2048; e += 64) {
    const int q = e >> 10, rc = e & 1023, r = rc >> 5, c = rc & 31;
    const float2 v = xf[rc];
    const float ps = psi0[(p0 + q) * 1024 + rc];
    Ar[q * 1056 + r * 33 + c] = v.x * ps;
    Ai[q * 1056 + r * 33 + c] = v.y * ps;
  }
  __syncthreads();
  { const int q = tid >> 5, r = tid & 31; fft_row<32, true>(Ar + q * 1056, Ai + q * 1056, r, 33); }
  __syncthreads();
  { // cols: inverse, |.|/1024, forward
    const int q = tid >> 5, col = tid & 31;
    float* re = Ar + q * 1056; float* im = Ai + q * 1056;
    float2 a[32];
    #pragma unroll
    for (int i = 0; i < 32; ++i) a[i] = make_float2(re[i * 33 + col], im[i * 33 + col]);
    fft1d<32, true>(a);
    #pragma unroll
    for (int i = 0; i < 32; ++i) {
      const float m = sqrtf(a[i].x * a[i].x + a[i].y * a[i].y) * (1.0f / 1024.0f);
      a[i] = make_float2(m, 0.0f);
    }
    fft1d<32, false>(a);
    #pragma unroll
    for (int i = 0; i < 32; ++i) { re[i * 33 + col] = a[i].x; im[i * 33 + col] = a[i].y; }
  }
  __syncthreads();
  { const int q = tid >> 5, r = tid & 31; fft_row<32, false>(Ar + q * 1056, Ai + q * 1056, r, 33); }
  __syncthreads();

  // store u0f planes
  for (int e = tid; e < 2048; e += 64) {
    const int q = e >> 10, rc = e & 1023, r = rc >> 5, c = rc & 31;
    u0f_g[((size_t)bc * 8 + p0 + q) * 1024 + rc] =
        make_float2(Ar[q * 1056 + r * 33 + c], Ai[q * 1056 + r * 33 + c]);
  }
  // s1a subsample
  for (int e = tid; e < 128; e += 64) {
    const int q = e >> 6, u = (e >> 3) & 7, v = e & 7;
    float sr = 0.f, si = 0.f;
    #pragma unroll
    for (int i2 = 0; i2 < 4; ++i2)
      #pragma unroll
      for (int j2 = 0; j2 < 4; ++j2) {
        const int r = u + 8 * i2, c = v + 8 * j2;
        const float ph = phi[r * 32 + c];
        sr += Ar[q * 1056 + r * 33 + c] * ph;
        si += Ai[q * 1056 + r * 33 + c] * ph;
      }
    Sr[q * 72 + u * 9 + v] = sr * 0.0625f;
    Si[q * 72 + u * 9 + v] = si * 0.0625f;
  }
  __syncthreads();
  if (tid < 16) { const int q = tid >> 3, r = tid & 7; fft_row<8, true>(Sr + q * 72, Si + q * 72, r, 9); }
  __syncthreads();
  if (tid < 16) {
    const int q = tid >> 3, col = tid & 7;
    float2 a[8];
    #pragma unroll
    for (int i = 0; i < 8; ++i) a[i] = make_float2(Sr[q * 72 + i * 9 + col], Si[q * 72 + i * 9 + col]);
    fft1d<8, true>(a);
    float* fo = feat + ((size_t)bc * 81 + 1 + p0 + q) * 64;
    #pragma unroll
    for (int i = 0; i < 8; ++i) fo[i * 8 + col] = a[i].x * (1.0f / 64.0f);
  }
}

// ---------------------------------------------------------------------------
// k_o2: unified 16x16 modulus path. Source plane = xf[bc] (j1, ch 9+t2) or
// u0f[bc,t1] (order-2, ch 17+t1*8+t2). 4 t2-planes per block.
// grid 3456 (= (192+1536)*2), block 64.
// ---------------------------------------------------------------------------
__global__ __launch_bounds__(64) void k_o2(
    const float2* __restrict__ xf_g, const float2* __restrict__ u0f_g,
    const float* __restrict__ psi1, const float* __restrict__ phi,
    float* __restrict__ feat)
{
  __shared__ float Ur[1056], Ui[1056];   // src 32x33
  __shared__ float Cr[1088], Ci[1088];   // 4 x 16x17
  __shared__ float Sr[288],  Si[288];    // 4 x 8x9
  __shared__ float P1[272];              // 16x17
  const int tid = threadIdx.x;
  const int blk = blockIdx.x;
  const int sp = blk >> 1, t2b = (blk & 1) * 4;
  const float2* src;
  int bc, chbase;
  if (sp < 192) { bc = sp; src = xf_g + (size_t)sp * 1024; chbase = 9; }
  else {
    const int s2 = sp - 192;
    bc = s2 >> 3;
    const int t1 = s2 & 7;
    src = u0f_g + ((size_t)bc * 8 + t1) * 1024;
    chbase = 17 + t1 * 8;
  }

  for (int e = tid; e < 1024; e += 64) {
    const float2 v = src[e];
    Ur[(e >> 5) * 33 + (e & 31)] = v.x;
    Ui[(e >> 5) * 33 + (e & 31)] = v.y;
  }
  for (int e = tid; e < 256; e += 64) {
    const int u = e >> 4, v = e & 15;
    P1[u * 17 + v] = 0.25f * (phi[u * 32 + v] + phi[u * 32 + v + 16] +
                              phi[(u + 16) * 32 + v] + phi[(u + 16) * 32 + v + 16]);
  }
  __syncthreads();
  // C[q] = (1/4) sum_{2x2} src * psi1[t2b+q]
  for (int e = tid; e < 1024; e += 64) {
    const int q = e >> 8, u = (e >> 4) & 15, v = e & 15;
    const int t2 = t2b + q;
    float sr = 0.f, si = 0.f;
    #pragma unroll
    for (int i2 = 0; i2 < 2; ++i2)
      #pragma unroll
      for (int j2 = 0; j2 < 2; ++j2) {
        const int r = u + 16 * i2, c = v + 16 * j2;
        const float ps = psi1[t2 * 1024 + r * 32 + c];
        sr += Ur[r * 33 + c] * ps;
        si += Ui[r * 33 + c] * ps;
      }
    Cr[q * 272 + u * 17 + v] = 0.25f * sr;
    Ci[q * 272 + u * 17 + v] = 0.25f * si;
  }
  __syncthreads();
  { const int q = tid >> 4, r = tid & 15; fft_row<16, true>(Cr + q * 272, Ci + q * 272, r, 17); }
  __syncthreads();
  { // cols: inverse, |.|/256, forward
    const int q = tid >> 4, col = tid & 15;
    float* re = Cr + q * 272; float* im = Ci + q * 272;
    float2 a[16];
    #pragma unroll
    for (int i = 0; i < 16; ++i) a[i] = make_float2(re[i * 17 + col], im[i * 17 + col]);
    fft1d<16, true>(a);
    #pragma unroll
    for (int i = 0; i < 16; ++i) {
      const float m = sqrtf(a[i].x * a[i].x + a[i].y * a[i].y) * (1.0f / 256.0f);
      a[i] = make_float2(m, 0.0f);
    }
    fft1d<16, false>(a);
    #pragma unroll
    for (int i = 0; i < 16; ++i) { re[i * 17 + col] = a[i].x; im[i * 17 + col] = a[i].y; }
  }
  __syncthreads();
  { const int q = tid >> 4, r = tid & 15; fft_row<16, false>(Cr + q * 272, Ci + q * 272, r, 17); }
  __syncthreads();
  // Z8 = (1/4) sum_{2x2} u2f * phi1
  for (int e = tid; e < 256; e += 64) {
    const int q = e >> 6, u = (e >> 3) & 7, v = e & 7;
    float sr = 0.f, si = 0.f;
    #pragma unroll
    for (int i2 = 0; i2 < 2; ++i2)
      #pragma unroll
      for (int j2 = 0; j2 < 2; ++j2) {
        const int r = u + 8 * i2, c = v + 8 * j2;
        const float ph = P1[r * 17 + c];
        sr += Cr[q * 272 + r * 17 + c] * ph;
        si += Ci[q * 272 + r * 17 + c] * ph;
      }
    Sr[q * 72 + u * 9 + v] = 0.25f * sr;
    Si[q * 72 + u * 9 + v] = 0.25f * si;
  }
  __syncthreads();
  if (tid < 32) { const int q = tid >> 3, r = tid & 7; fft_row<8, true>(Sr + q * 72, Si + q * 72, r, 9); }
  __syncthreads();
  if (tid < 32) {
    const int q = tid >> 3, col = tid & 7;
    float2 a[8];
    #pragma unroll
    for (int i = 0; i < 8; ++i) a[i] = make_float2(Sr[q * 72 + i * 9 + col], Si[q * 72 + i * 9 + col]);
    fft1d<8, true>(a);
    float* fo = feat + ((size_t)bc * 81 + chbase + t2b + q) * 64;
    #pragma unroll
    for (int i = 0; i < 8; ++i) fo[i * 8 + col] = a[i].x * (1.0f / 64.0f);
  }
}

// ---------------------------------------------------------------------------
// k_gnlin: GroupNorm(27) + Linear(15552->10). grid 64, block 256.
// ---------------------------------------------------------------------------
__global__ __launch_bounds__(256) void k_gnlin(
    const float* __restrict__ feat, const float* __restrict__ gamma,
    const float* __restrict__ beta, const float* __restrict__ W,
    const float* __restrict__ bias, float* __restrict__ out)
{
  __shared__ float F[15552];
  __shared__ float gmu[27], grs[27];
  __shared__ float red[40];
  const int tid = threadIdx.x, b = blockIdx.x;
  const float* fp = feat + (size_t)b * 15552;
  for (int e = tid; e < 15552; e += 256) F[e] = fp[e];
  __syncthreads();
  if (tid < 216) {
    const int g = tid >> 3, l8 = tid & 7;
    float s = 0.f, ss = 0.f;
    for (int e = l8; e < 576; e += 8) { const float v = F[g * 576 + e]; s += v; ss += v * v; }
    #pragma unroll
    for (int off = 1; off < 8; off <<= 1) { s += __shfl_down(s, off); ss += __shfl_down(ss, off); }
    if (l8 == 0) {
      const float mu = s * (1.0f / 576.0f);
      gmu[g] = mu;
      grs[g] = rsqrtf(ss * (1.0f / 576.0f) - mu * mu + 1e-5f);
    }
  }
  __syncthreads();
  for (int e = tid; e < 15552; e += 256) {
    const int ch = e >> 6, g = ch / 9;
    F[e] = (F[e] - gmu[g]) * grs[g] * gamma[ch] + beta[ch];
  }
  __syncthreads();
  float acc[10];
  #pragma unroll
  for (int k = 0; k < 10; ++k) acc[k] = 0.f;
  const float4* F4 = reinterpret_cast<const float4*>(F);
  for (int i4 = tid; i4 < 3888; i4 += 256) {
    const float4 f = F4[i4];
    #pragma unroll
    for (int k = 0; k < 10; ++k) {
      const float4 w = *reinterpret_cast<const float4*>(&W[(size_t)k * 15552 + i4 * 4]);
      acc[k] = fmaf(f.x, w.x, fmaf(f.y, w.y, fmaf(f.z, w.z, fmaf(f.w, w.w, acc[k]))));
    }
  }
  #pragma unroll
  for (int k = 0; k < 10; ++k) {
    float v = acc[k];
    #pragma unroll
    for (int off = 32; off > 0; off >>= 1) v += __shfl_down(v, off);
    if ((tid & 63) == 0) red[(tid >> 6) * 10 + k] = v;
  }
  __syncthreads();
  if (tid < 10) out[b * 10 + tid] = red[tid] + red[10 + tid] + red[20 + tid] + red[30 + tid] + bias[tid];
}

// ---------------------------------------------------------------------------
extern "C" void kernel_launch(void* const* d_in, const int* in_sizes, int n_in,
                              void* d_out, int out_size, void* d_ws, size_t ws_size,
                              hipStream_t stream) {
  (void)in_sizes; (void)n_in; (void)out_size; (void)ws_size;
  const float* x     = (const float*)d_in[0];
  const float* psi0  = (const float*)d_in[1];
  const float* psi1  = (const float*)d_in[2];
  const float* phi   = (const float*)d_in[3];
  const float* gamma = (const float*)d_in[4];
  const float* beta  = (const float*)d_in[5];
  const float* W     = (const float*)d_in[6];
  const float* bias  = (const float*)d_in[7];
  float* out = (float*)d_out;

  float2* xf_g  = (float2*)d_ws;                 // 192*1024 c64 = 1.5 MB
  float2* u0f_g = xf_g + (size_t)192 * 1024;     // 192*8*1024 c64 = 12.6 MB
  float*  feat  = (float*)(u0f_g + (size_t)192 * 8 * 1024);  // 64*15552 f32 = 4 MB

  hipLaunchKernelGGL(k_xf,    dim3(96),   dim3(64),  0, stream, x, phi, xf_g, feat);
  hipLaunchKernelGGL(k_u0,    dim3(768),  dim3(64),  0, stream, xf_g, psi0, phi, u0f_g, feat);
  hipLaunchKernelGGL(k_o2,    dim3(3456), dim3(64),  0, stream, xf_g, u0f_g, psi1, phi, feat);
  hipLaunchKernelGGL(k_gnlin, dim3(64),   dim3(256), 0, stream, feat, gamma, beta, W, bias, out);
}

// Round 5
// 145.106 us; speedup vs baseline: 1.0861x; 1.0547x over previous
//
#include <hip/hip_runtime.h>
#include <math.h>

// ---------------------------------------------------------------------------
// Scattering (J=2,L=8,N=32) + GroupNorm(27) + Linear(15552->10), round 5.
// Same structure as round 4; FIX: Sr/Si in k_scatter1 sized 288 (4 planes x 72)
// — the j1=1 branch writes 4 subsample planes; 216 overflowed into Si/P1.
//   k_scatter1 (1152 blocks x 64): u0 path (+s0,s1a) and j1=1 path (s1b)
//   k_o2       (1536 blocks x 64): per (bc,t1) all 8 t2-planes -> s2
//   k_gnlin    (64 blocks x 256): GroupNorm + GEMV(float4) -> out
// ---------------------------------------------------------------------------

constexpr float C32T[32] = {
  1.0000000000f, 0.9807852804f, 0.9238795325f, 0.8314696123f,
  0.7071067812f, 0.5555702330f, 0.3826834324f, 0.1950903220f,
  0.0000000000f,-0.1950903220f,-0.3826834324f,-0.5555702330f,
 -0.7071067812f,-0.8314696123f,-0.9238795325f,-0.9807852804f,
 -1.0000000000f,-0.9807852804f,-0.9238795325f,-0.8314696123f,
 -0.7071067812f,-0.5555702330f,-0.3826834324f,-0.1950903220f,
  0.0000000000f, 0.1950903220f, 0.3826834324f, 0.5555702330f,
  0.7071067812f, 0.8314696123f, 0.9238795325f, 0.9807852804f };
constexpr float S32T[32] = {
  0.0000000000f, 0.1950903220f, 0.3826834324f, 0.5555702330f,
  0.7071067812f, 0.8314696123f, 0.9238795325f, 0.9807852804f,
  1.0000000000f, 0.9807852804f, 0.9238795325f, 0.8314696123f,
  0.7071067812f, 0.5555702330f, 0.3826834324f, 0.1950903220f,
  0.0000000000f,-0.1950903220f,-0.3826834324f,-0.5555702330f,
 -0.7071067812f,-0.8314696123f,-0.9238795325f,-0.9807852804f,
 -1.0000000000f,-0.9807852804f,-0.9238795325f,-0.8314696123f,
 -0.7071067812f,-0.5555702330f,-0.3826834324f,-0.1950903220f };

template<int N, bool INV>
__device__ __forceinline__ void fft1d(float2 (&a)[N]) {
  constexpr int LOG = (N == 32) ? 5 : ((N == 16) ? 4 : 3);
  #pragma unroll
  for (int i = 0; i < N; ++i) {
    int j = 0;
    #pragma unroll
    for (int bn = 0; bn < LOG; ++bn) j |= ((i >> bn) & 1) << (LOG - 1 - bn);
    if (j > i) { float2 t = a[i]; a[i] = a[j]; a[j] = t; }
  }
  #pragma unroll
  for (int s = 1; s <= LOG; ++s) {
    const int half  = 1 << (s - 1);
    const int tstep = 32 >> s;
    #pragma unroll
    for (int i = 0; i < N; i += (1 << s)) {
      #pragma unroll
      for (int k = 0; k < half; ++k) {
        const int   ti = k * tstep;
        const float wr = C32T[ti];
        const float wi = INV ? S32T[ti] : -S32T[ti];
        const float2 u = a[i + k];
        const float2 v = a[i + k + half];
        const float tr = v.x * wr - v.y * wi;
        const float tq = v.x * wi + v.y * wr;
        a[i + k]        = make_float2(u.x + tr, u.y + tq);
        a[i + k + half] = make_float2(u.x - tr, u.y - tq);
      }
    }
  }
}

template<int N, bool INV>
__device__ __forceinline__ void fft_row(float* re, float* im, int row, int LD) {
  float2 a[N];
  #pragma unroll
  for (int i = 0; i < N; ++i) a[i] = make_float2(re[row * LD + i], im[row * LD + i]);
  fft1d<N, INV>(a);
  #pragma unroll
  for (int i = 0; i < N; ++i) { re[row * LD + i] = a[i].x; im[row * LD + i] = a[i].y; }
}

template<int N, bool INV>
__device__ __forceinline__ void fft_col(float* re, float* im, int col, int LD) {
  float2 a[N];
  #pragma unroll
  for (int i = 0; i < N; ++i) a[i] = make_float2(re[i * LD + col], im[i * LD + col]);
  fft1d<N, INV>(a);
  #pragma unroll
  for (int i = 0; i < N; ++i) { re[i * LD + col] = a[i].x; im[i * LD + col] = a[i].y; }
}

// ---------------------------------------------------------------------------
// k_scatter1: grid 1152, block 64.
// ---------------------------------------------------------------------------
__global__ __launch_bounds__(64) void k_scatter1(
    const float* __restrict__ x, const float* __restrict__ psi0,
    const float* __restrict__ psi1, const float* __restrict__ phi,
    float2* __restrict__ u0f_g, float* __restrict__ feat)
{
  __shared__ float Xr[1056], Xi[1056];   // xf 32x33
  __shared__ float Ar[2112], Ai[2112];   // 2 x 32x33 (u0 pair) OR 4 x 16x17 (j1)
  __shared__ float Sr[288],  Si[288];    // up to 4 planes of 8x9  (FIXED: was 216)
  __shared__ float P1[272];              // 16x17 (j1 blocks only)
  const int tid = threadIdx.x;
  const int blk = blockIdx.x;
  const bool is_u0 = blk < 768;
  const int bc = is_u0 ? (blk >> 2) : ((blk - 768) >> 1);

  // ---- load x, (j1 blocks also phi1), then xf = fft2(x) ----
  for (int e = tid; e < 1024; e += 64) {
    Xr[(e >> 5) * 33 + (e & 31)] = x[bc * 1024 + e];
    Xi[(e >> 5) * 33 + (e & 31)] = 0.0f;
  }
  if (!is_u0) {
    for (int e = tid; e < 256; e += 64) {
      const int u = e >> 4, v = e & 15;
      P1[u * 17 + v] = 0.25f * (phi[u * 32 + v] + phi[u * 32 + v + 16] +
                                phi[(u + 16) * 32 + v] + phi[(u + 16) * 32 + v + 16]);
    }
  }
  __syncthreads();
  if (tid < 32) fft_row<32, false>(Xr, Xi, tid, 33);
  __syncthreads();
  if (tid < 32) fft_col<32, false>(Xr, Xi, tid, 33);
  __syncthreads();

  if (is_u0) {
    // ---- j1=0 path: planes p0, p0+1 ----
    const int p0 = (blk & 3) * 2;
    for (int e = tid; e < 2048; e += 64) {
      const int q = e >> 10, rc = e & 1023, r = rc >> 5, c = rc & 31;
      const float ps = psi0[(p0 + q) * 1024 + rc];
      Ar[q * 1056 + r * 33 + c] = Xr[r * 33 + c] * ps;
      Ai[q * 1056 + r * 33 + c] = Xi[r * 33 + c] * ps;
    }
    __syncthreads();
    { const int q = tid >> 5, r = tid & 31; fft_row<32, true>(Ar + q * 1056, Ai + q * 1056, r, 33); }
    __syncthreads();
    { // cols: inverse, |.|/1024, forward
      const int q = tid >> 5, col = tid & 31;
      float* re = Ar + q * 1056; float* im = Ai + q * 1056;
      float2 a[32];
      #pragma unroll
      for (int i = 0; i < 32; ++i) a[i] = make_float2(re[i * 33 + col], im[i * 33 + col]);
      fft1d<32, true>(a);
      #pragma unroll
      for (int i = 0; i < 32; ++i) {
        const float m = sqrtf(a[i].x * a[i].x + a[i].y * a[i].y) * (1.0f / 1024.0f);
        a[i] = make_float2(m, 0.0f);
      }
      fft1d<32, false>(a);
      #pragma unroll
      for (int i = 0; i < 32; ++i) { re[i * 33 + col] = a[i].x; im[i * 33 + col] = a[i].y; }
    }
    __syncthreads();
    { const int q = tid >> 5, r = tid & 31; fft_row<32, false>(Ar + q * 1056, Ai + q * 1056, r, 33); }
    __syncthreads();
    // store u0f planes (coalesced float2)
    for (int e = tid; e < 2048; e += 64) {
      const int q = e >> 10, rc = e & 1023, r = rc >> 5, c = rc & 31;
      u0f_g[((size_t)bc * 8 + p0 + q) * 1024 + rc] =
          make_float2(Ar[q * 1056 + r * 33 + c], Ai[q * 1056 + r * 33 + c]);
    }
    // subsample: planes 0,1 = s1a(p0+q); plane 2 (pair 0 only) = s0 from xf
    const int nsp = (p0 == 0) ? 3 : 2;
    for (int e = tid; e < nsp * 64; e += 64) {
      const int p = e >> 6, u = (e >> 3) & 7, v = e & 7;
      float sr = 0.f, si = 0.f;
      #pragma unroll
      for (int i2 = 0; i2 < 4; ++i2)
        #pragma unroll
        for (int j2 = 0; j2 < 4; ++j2) {
          const int r = u + 8 * i2, c = v + 8 * j2;
          const float ph = phi[r * 32 + c];
          float vr, vi;
          if (p == 2) { vr = Xr[r * 33 + c]; vi = Xi[r * 33 + c]; }
          else        { vr = Ar[p * 1056 + r * 33 + c]; vi = Ai[p * 1056 + r * 33 + c]; }
          sr += vr * ph; si += vi * ph;
        }
      Sr[p * 72 + u * 9 + v] = sr * 0.0625f;
      Si[p * 72 + u * 9 + v] = si * 0.0625f;
    }
    __syncthreads();
    if (tid < nsp * 8) { const int p = tid >> 3, r = tid & 7; fft_row<8, true>(Sr + p * 72, Si + p * 72, r, 9); }
    __syncthreads();
    if (tid < nsp * 8) {
      const int p = tid >> 3, col = tid & 7;
      float2 a[8];
      #pragma unroll
      for (int i = 0; i < 8; ++i) a[i] = make_float2(Sr[p * 72 + i * 9 + col], Si[p * 72 + i * 9 + col]);
      fft1d<8, true>(a);
      const int ch = (p == 2) ? 0 : (1 + p0 + p);
      float* fo = feat + ((size_t)bc * 81 + ch) * 64;
      #pragma unroll
      for (int i = 0; i < 8; ++i) fo[i * 8 + col] = a[i].x * (1.0f / 64.0f);
    }
  } else {
    // ---- j1=1 path: 4 t2-planes, 16x16 modulus pipeline ----
    const int t2b = ((blk - 768) & 1) * 4;
    float* Cr = Ar; float* Ci = Ai;      // 4 x 16x17 = 1088 <= 2112
    for (int e = tid; e < 1024; e += 64) {
      const int q = e >> 8, u = (e >> 4) & 15, v = e & 15;
      const int t2 = t2b + q;
      float sr = 0.f, si = 0.f;
      #pragma unroll
      for (int i2 = 0; i2 < 2; ++i2)
        #pragma unroll
        for (int j2 = 0; j2 < 2; ++j2) {
          const int r = u + 16 * i2, c = v + 16 * j2;
          const float ps = psi1[t2 * 1024 + r * 32 + c];
          sr += Xr[r * 33 + c] * ps;
          si += Xi[r * 33 + c] * ps;
        }
      Cr[q * 272 + u * 17 + v] = 0.25f * sr;
      Ci[q * 272 + u * 17 + v] = 0.25f * si;
    }
    __syncthreads();
    { const int q = tid >> 4, r = tid & 15; fft_row<16, true>(Cr + q * 272, Ci + q * 272, r, 17); }
    __syncthreads();
    { const int q = tid >> 4, col = tid & 15;
      float* re = Cr + q * 272; float* im = Ci + q * 272;
      float2 a[16];
      #pragma unroll
      for (int i = 0; i < 16; ++i) a[i] = make_float2(re[i * 17 + col], im[i * 17 + col]);
      fft1d<16, true>(a);
      #pragma unroll
      for (int i = 0; i < 16; ++i) {
        const float m = sqrtf(a[i].x * a[i].x + a[i].y * a[i].y) * (1.0f / 256.0f);
        a[i] = make_float2(m, 0.0f);
      }
      fft1d<16, false>(a);
      #pragma unroll
      for (int i = 0; i < 16; ++i) { re[i * 17 + col] = a[i].x; im[i * 17 + col] = a[i].y; }
    }
    __syncthreads();
    { const int q = tid >> 4, r = tid & 15; fft_row<16, false>(Cr + q * 272, Ci + q * 272, r, 17); }
    __syncthreads();
    for (int e = tid; e < 256; e += 64) {
      const int q = e >> 6, u = (e >> 3) & 7, v = e & 7;
      float sr = 0.f, si = 0.f;
      #pragma unroll
      for (int i2 = 0; i2 < 2; ++i2)
        #pragma unroll
        for (int j2 = 0; j2 < 2; ++j2) {
          const int r = u + 8 * i2, c = v + 8 * j2;
          const float ph = P1[r * 17 + c];
          sr += Cr[q * 272 + r * 17 + c] * ph;
          si += Ci[q * 272 + r * 17 + c] * ph;
        }
      Sr[q * 72 + u * 9 + v] = 0.25f * sr;
      Si[q * 72 + u * 9 + v] = 0.25f * si;
    }
    __syncthreads();
    if (tid < 32) { const int q = tid >> 3, r = tid & 7; fft_row<8, true>(Sr + q * 72, Si + q * 72, r, 9); }
    __syncthreads();
    if (tid < 32) {
      const int q = tid >> 3, col = tid & 7;
      float2 a[8];
      #pragma unroll
      for (int i = 0; i < 8; ++i) a[i] = make_float2(Sr[q * 72 + i * 9 + col], Si[q * 72 + i * 9 + col]);
      fft1d<8, true>(a);
      float* fo = feat + ((size_t)bc * 81 + 9 + t2b + q) * 64;
      #pragma unroll
      for (int i = 0; i < 8; ++i) fo[i * 8 + col] = a[i].x * (1.0f / 64.0f);
    }
  }
}

// ---------------------------------------------------------------------------
// k_o2: one block per (bc,t1); all 8 t2-planes in 2 rounds of 4.
// grid 1536, block 64.
// ---------------------------------------------------------------------------
__global__ __launch_bounds__(64) void k_o2(
    const float2* __restrict__ u0f_g, const float* __restrict__ psi1,
    const float* __restrict__ phi, float* __restrict__ feat)
{
  __shared__ float Ur[1056], Ui[1056];   // u0f plane 32x33
  __shared__ float Cr[1088], Ci[1088];   // 4 x 16x17
  __shared__ float Sr[288],  Si[288];    // 4 x 8x9
  __shared__ float P1[272];
  const int tid = threadIdx.x;
  const int blk = blockIdx.x;
  const int bc = blk >> 3, t1 = blk & 7;
  const float2* src = u0f_g + ((size_t)bc * 8 + t1) * 1024;

  for (int e = tid; e < 1024; e += 64) {
    const float2 v = src[e];
    Ur[(e >> 5) * 33 + (e & 31)] = v.x;
    Ui[(e >> 5) * 33 + (e & 31)] = v.y;
  }
  for (int e = tid; e < 256; e += 64) {
    const int u = e >> 4, v = e & 15;
    P1[u * 17 + v] = 0.25f * (phi[u * 32 + v] + phi[u * 32 + v + 16] +
                              phi[(u + 16) * 32 + v] + phi[(u + 16) * 32 + v + 16]);
  }
  __syncthreads();

  for (int round = 0; round < 2; ++round) {
    const int t2b = round * 4;
    for (int e = tid; e < 1024; e += 64) {
      const int q = e >> 8, u = (e >> 4) & 15, v = e & 15;
      const int t2 = t2b + q;
      float sr = 0.f, si = 0.f;
      #pragma unroll
      for (int i2 = 0; i2 < 2; ++i2)
        #pragma unroll
        for (int j2 = 0; j2 < 2; ++j2) {
          const int r = u + 16 * i2, c = v + 16 * j2;
          const float ps = psi1[t2 * 1024 + r * 32 + c];
          sr += Ur[r * 33 + c] * ps;
          si += Ui[r * 33 + c] * ps;
        }
      Cr[q * 272 + u * 17 + v] = 0.25f * sr;
      Ci[q * 272 + u * 17 + v] = 0.25f * si;
    }
    __syncthreads();
    { const int q = tid >> 4, r = tid & 15; fft_row<16, true>(Cr + q * 272, Ci + q * 272, r, 17); }
    __syncthreads();
    { const int q = tid >> 4, col = tid & 15;
      float* re = Cr + q * 272; float* im = Ci + q * 272;
      float2 a[16];
      #pragma unroll
      for (int i = 0; i < 16; ++i) a[i] = make_float2(re[i * 17 + col], im[i * 17 + col]);
      fft1d<16, true>(a);
      #pragma unroll
      for (int i = 0; i < 16; ++i) {
        const float m = sqrtf(a[i].x * a[i].x + a[i].y * a[i].y) * (1.0f / 256.0f);
        a[i] = make_float2(m, 0.0f);
      }
      fft1d<16, false>(a);
      #pragma unroll
      for (int i = 0; i < 16; ++i) { re[i * 17 + col] = a[i].x; im[i * 17 + col] = a[i].y; }
    }
    __syncthreads();
    { const int q = tid >> 4, r = tid & 15; fft_row<16, false>(Cr + q * 272, Ci + q * 272, r, 17); }
    __syncthreads();
    for (int e = tid; e < 256; e += 64) {
      const int q = e >> 6, u = (e >> 3) & 7, v = e & 7;
      float sr = 0.f, si = 0.f;
      #pragma unroll
      for (int i2 = 0; i2 < 2; ++i2)
        #pragma unroll
        for (int j2 = 0; j2 < 2; ++j2) {
          const int r = u + 8 * i2, c = v + 8 * j2;
          const float ph = P1[r * 17 + c];
          sr += Cr[q * 272 + r * 17 + c] * ph;
          si += Ci[q * 272 + r * 17 + c] * ph;
        }
      Sr[q * 72 + u * 9 + v] = 0.25f * sr;
      Si[q * 72 + u * 9 + v] = 0.25f * si;
    }
    __syncthreads();
    if (tid < 32) { const int q = tid >> 3, r = tid & 7; fft_row<8, true>(Sr + q * 72, Si + q * 72, r, 9); }
    __syncthreads();
    if (tid < 32) {
      const int q = tid >> 3, col = tid & 7;
      float2 a[8];
      #pragma unroll
      for (int i = 0; i < 8; ++i) a[i] = make_float2(Sr[q * 72 + i * 9 + col], Si[q * 72 + i * 9 + col]);
      fft1d<8, true>(a);
      float* fo = feat + ((size_t)bc * 81 + 17 + t1 * 8 + t2b + q) * 64;
      #pragma unroll
      for (int i = 0; i < 8; ++i) fo[i * 8 + col] = a[i].x * (1.0f / 64.0f);
    }
    __syncthreads();
  }
}

// ---------------------------------------------------------------------------
// k_gnlin: GroupNorm(27) + Linear(15552->10). grid 64, block 256.
// ---------------------------------------------------------------------------
__global__ __launch_bounds__(256) void k_gnlin(
    const float* __restrict__ feat, const float* __restrict__ gamma,
    const float* __restrict__ beta, const float* __restrict__ W,
    const float* __restrict__ bias, float* __restrict__ out)
{
  __shared__ float F[15552];
  __shared__ float gmu[27], grs[27];
  __shared__ float red[40];
  const int tid = threadIdx.x, b = blockIdx.x;
  const float* fp = feat + (size_t)b * 15552;
  for (int e = tid; e < 15552; e += 256) F[e] = fp[e];
  __syncthreads();
  if (tid < 216) {
    const int g = tid >> 3, l8 = tid & 7;
    float s = 0.f, ss = 0.f;
    for (int e = l8; e < 576; e += 8) { const float v = F[g * 576 + e]; s += v; ss += v * v; }
    #pragma unroll
    for (int off = 1; off < 8; off <<= 1) { s += __shfl_down(s, off); ss += __shfl_down(ss, off); }
    if (l8 == 0) {
      const float mu = s * (1.0f / 576.0f);
      gmu[g] = mu;
      grs[g] = rsqrtf(ss * (1.0f / 576.0f) - mu * mu + 1e-5f);
    }
  }
  __syncthreads();
  for (int e = tid; e < 15552; e += 256) {
    const int ch = e >> 6, g = ch / 9;
    F[e] = (F[e] - gmu[g]) * grs[g] * gamma[ch] + beta[ch];
  }
  __syncthreads();
  float acc[10];
  #pragma unroll
  for (int k = 0; k < 10; ++k) acc[k] = 0.f;
  const float4* F4 = reinterpret_cast<const float4*>(F);
  for (int i4 = tid; i4 < 3888; i4 += 256) {
    const float4 f = F4[i4];
    #pragma unroll
    for (int k = 0; k < 10; ++k) {
      const float4 w = *reinterpret_cast<const float4*>(&W[(size_t)k * 15552 + i4 * 4]);
      acc[k] = fmaf(f.x, w.x, fmaf(f.y, w.y, fmaf(f.z, w.z, fmaf(f.w, w.w, acc[k]))));
    }
  }
  #pragma unroll
  for (int k = 0; k < 10; ++k) {
    float v = acc[k];
    #pragma unroll
    for (int off = 32; off > 0; off >>= 1) v += __shfl_down(v, off);
    if ((tid & 63) == 0) red[(tid >> 6) * 10 + k] = v;
  }
  __syncthreads();
  if (tid < 10) out[b * 10 + tid] = red[tid] + red[10 + tid] + red[20 + tid] + red[30 + tid] + bias[tid];
}

// ---------------------------------------------------------------------------
extern "C" void kernel_launch(void* const* d_in, const int* in_sizes, int n_in,
                              void* d_out, int out_size, void* d_ws, size_t ws_size,
                              hipStream_t stream) {
  (void)in_sizes; (void)n_in; (void)out_size; (void)ws_size;
  const float* x     = (const float*)d_in[0];
  const float* psi0  = (const float*)d_in[1];
  const float* psi1  = (const float*)d_in[2];
  const float* phi   = (const float*)d_in[3];
  const float* gamma = (const float*)d_in[4];
  const float* beta  = (const float*)d_in[5];
  const float* W     = (const float*)d_in[6];
  const float* bias  = (const float*)d_in[7];
  float* out = (float*)d_out;

  float2* u0f_g = (float2*)d_ws;                         // 192*8*1024 c64 = 12.6 MB
  float*  feat  = (float*)(u0f_g + (size_t)192 * 8 * 1024);  // 64*15552 f32 = 4 MB

  hipLaunchKernelGGL(k_scatter1, dim3(1152), dim3(64),  0, stream, x, psi0, psi1, phi, u0f_g, feat);
  hipLaunchKernelGGL(k_o2,       dim3(1536), dim3(64),  0, stream, u0f_g, psi1, phi, feat);
  hipLaunchKernelGGL(k_gnlin,    dim3(64),   dim3(256), 0, stream, feat, gamma, beta, W, bias, out);
}